// Round 1
// baseline (233.395 us; speedup 1.0000x reference)
//
#include <hip/hip_runtime.h>
#include <hip/hip_bf16.h>

#define N_TOK 8192
#define D_IN  1024
#define DK    128

typedef __attribute__((ext_vector_type(8))) short short8;
typedef __attribute__((ext_vector_type(4))) float f32x4;

static __device__ __forceinline__ unsigned short f2bf(float f) {
    __hip_bfloat16 h = __float2bfloat16(f);
    return __builtin_bit_cast(unsigned short, h);
}

// ---------------- QKV projection: out = X @ W + b, bf16 outputs ----------------
// grid = (64, 3): blockIdx.x = 128-row tile, blockIdx.y = which projection.
// Q,K stored row-major [8192][128]; V stored transposed [128][8192].
__global__ __launch_bounds__(256) void proj_kernel(
    const float* __restrict__ X,
    const float* __restrict__ Wq, const float* __restrict__ bq,
    const float* __restrict__ Wk, const float* __restrict__ bk,
    const float* __restrict__ Wv, const float* __restrict__ bv,
    unsigned short* __restrict__ Qb, unsigned short* __restrict__ Kb,
    unsigned short* __restrict__ Vt)
{
    __shared__ unsigned short As[128][72];  // [m][k], pad 64->72 (2-way on read = free)
    __shared__ unsigned short Bs[128][72];  // [n][k] (W transposed)

    const int tid  = threadIdx.x;
    const int wid  = tid >> 6, lane = tid & 63;
    const int g    = lane >> 4, r16 = lane & 15;
    const int wm   = wid >> 1, wn = wid & 1;
    const int mb   = blockIdx.x * 128;
    const int proj = blockIdx.y;

    const float* W    = (proj == 0) ? Wq : (proj == 1) ? Wk : Wv;
    const float* bias = (proj == 0) ? bq : (proj == 1) ? bk : bv;

    f32x4 acc[4][4] = {};

    for (int k0 = 0; k0 < D_IN; k0 += 64) {
        // stage A: X[mb..mb+128][k0..k0+64] -> bf16
        #pragma unroll
        for (int i = 0; i < 8; i++) {
            int e = tid + i * 256;          // 2048 float4s
            int r = e >> 4, c4 = e & 15;
            const float4 v = *reinterpret_cast<const float4*>(
                &X[(size_t)(mb + r) * D_IN + k0 + c4 * 4]);
            ushort4 h;
            h.x = f2bf(v.x); h.y = f2bf(v.y); h.z = f2bf(v.z); h.w = f2bf(v.w);
            *reinterpret_cast<ushort4*>(&As[r][c4 * 4]) = h;
        }
        // stage B transposed: Bs[n][kk] = W[k0+kk][n]
        #pragma unroll
        for (int i = 0; i < 8; i++) {
            int e = tid + i * 256;          // 2048 float4s
            int kk = e >> 5, c4 = e & 31;
            const float4 v = *reinterpret_cast<const float4*>(
                &W[(size_t)(k0 + kk) * DK + c4 * 4]);
            Bs[c4 * 4 + 0][kk] = f2bf(v.x);
            Bs[c4 * 4 + 1][kk] = f2bf(v.y);
            Bs[c4 * 4 + 2][kk] = f2bf(v.z);
            Bs[c4 * 4 + 3][kk] = f2bf(v.w);
        }
        __syncthreads();
        #pragma unroll
        for (int kk = 0; kk < 64; kk += 32) {
            short8 af[4], bfr[4];
            #pragma unroll
            for (int mi = 0; mi < 4; mi++)
                af[mi] = *reinterpret_cast<const short8*>(&As[wm * 64 + mi * 16 + r16][kk + g * 8]);
            #pragma unroll
            for (int ni = 0; ni < 4; ni++)
                bfr[ni] = *reinterpret_cast<const short8*>(&Bs[wn * 64 + ni * 16 + r16][kk + g * 8]);
            #pragma unroll
            for (int mi = 0; mi < 4; mi++)
                #pragma unroll
                for (int ni = 0; ni < 4; ni++)
                    acc[mi][ni] = __builtin_amdgcn_mfma_f32_16x16x32_bf16(
                        af[mi], bfr[ni], acc[mi][ni], 0, 0, 0);
        }
        __syncthreads();
    }

    if (proj < 2) {
        unsigned short* out = (proj == 0) ? Qb : Kb;
        #pragma unroll
        for (int ni = 0; ni < 4; ni++) {
            int n = wn * 64 + ni * 16 + r16;
            float b = bias[n];
            #pragma unroll
            for (int mi = 0; mi < 4; mi++) {
                #pragma unroll
                for (int e = 0; e < 4; e++) {
                    int m = mb + wm * 64 + mi * 16 + g * 4 + e;
                    out[(size_t)m * DK + n] = f2bf(acc[mi][ni][e] + b);
                }
            }
        }
    } else {
        #pragma unroll
        for (int ni = 0; ni < 4; ni++) {
            int n = wn * 64 + ni * 16 + r16;
            float b = bias[n];
            #pragma unroll
            for (int mi = 0; mi < 4; mi++) {
                int m0 = mb + wm * 64 + mi * 16 + g * 4;
                ushort4 h;
                h.x = f2bf(acc[mi][ni][0] + b);
                h.y = f2bf(acc[mi][ni][1] + b);
                h.z = f2bf(acc[mi][ni][2] + b);
                h.w = f2bf(acc[mi][ni][3] + b);
                *reinterpret_cast<ushort4*>(&Vt[(size_t)n * N_TOK + m0]) = h;
            }
        }
    }
}

// ---------------- causal flash attention ----------------
// grid = 256 blocks; block t owns q rows [t*32, t*32+32). 4 waves split the
// kv range (wave w takes kv tiles j = w, w+4, ...), merged at the end.
__global__ __launch_bounds__(256) void attn_kernel(
    const unsigned short* __restrict__ Qb, const unsigned short* __restrict__ Kb,
    const unsigned short* __restrict__ Vt, float* __restrict__ O)
{
    __shared__ float          O_merge[32][128];        // 16 KB
    __shared__ float          m_lds[4][32], l_lds[4][32];
    __shared__ unsigned short P_lds[4][32][40];        // per-wave P transpose, pad 32->40

    const int tid = threadIdx.x;
    const int wid = tid >> 6, lane = tid & 63;
    const int g = lane >> 4, r16 = lane & 15;
    const int t = blockIdx.x;
    const int qbase = t * 32;
    const float scale = 0.08838834764831845f;  // 1/sqrt(128)

    // Q fragments in registers: [mi][kd]
    short8 qf[2][4];
    #pragma unroll
    for (int mi = 0; mi < 2; mi++)
        #pragma unroll
        for (int kd = 0; kd < 4; kd++)
            qf[mi][kd] = *reinterpret_cast<const short8*>(
                &Qb[(size_t)(qbase + mi * 16 + r16) * DK + kd * 32 + g * 8]);

    f32x4 o_acc[2][8] = {};
    float m_run[2][4], l_run[2][4];
    #pragma unroll
    for (int mi = 0; mi < 2; mi++)
        #pragma unroll
        for (int e = 0; e < 4; e++) { m_run[mi][e] = -1e30f; l_run[mi][e] = 0.f; }

    for (int j = wid; j <= t; j += 4) {
        const int kvb = j * 32;
        // ---- S = Q K^T ----
        f32x4 sacc[2][2] = {};
        #pragma unroll
        for (int kd = 0; kd < 4; kd++) {
            short8 kf[2];
            #pragma unroll
            for (int ni = 0; ni < 2; ni++)
                kf[ni] = *reinterpret_cast<const short8*>(
                    &Kb[(size_t)(kvb + ni * 16 + r16) * DK + kd * 32 + g * 8]);
            #pragma unroll
            for (int mi = 0; mi < 2; mi++)
                #pragma unroll
                for (int ni = 0; ni < 2; ni++)
                    sacc[mi][ni] = __builtin_amdgcn_mfma_f32_16x16x32_bf16(
                        qf[mi][kd], kf[ni], sacc[mi][ni], 0, 0, 0);
        }
        // ---- online softmax (row = mi*16 + g*4 + e, col = ni*16 + r16) ----
        float p[2][2][4], alpha[2][4];
        #pragma unroll
        for (int mi = 0; mi < 2; mi++) {
            #pragma unroll
            for (int e = 0; e < 4; e++) {
                float s0 = sacc[mi][0][e] * scale;
                float s1 = sacc[mi][1][e] * scale;
                if (j == t) {  // diagonal tile: mask col > row
                    int row = mi * 16 + g * 4 + e;
                    if (r16 > row)      s0 = -1e30f;
                    if (16 + r16 > row) s1 = -1e30f;
                }
                float rm = fmaxf(s0, s1);
                rm = fmaxf(rm, __shfl_xor(rm, 1));
                rm = fmaxf(rm, __shfl_xor(rm, 2));
                rm = fmaxf(rm, __shfl_xor(rm, 4));
                rm = fmaxf(rm, __shfl_xor(rm, 8));
                float mnew = fmaxf(m_run[mi][e], rm);
                float a  = __expf(m_run[mi][e] - mnew);
                float p0 = __expf(s0 - mnew);
                float p1 = __expf(s1 - mnew);
                float rs = p0 + p1;
                rs += __shfl_xor(rs, 1);
                rs += __shfl_xor(rs, 2);
                rs += __shfl_xor(rs, 4);
                rs += __shfl_xor(rs, 8);
                l_run[mi][e] = l_run[mi][e] * a + rs;
                m_run[mi][e] = mnew;
                alpha[mi][e] = a;
                p[mi][0][e] = p0; p[mi][1][e] = p1;
            }
        }
        // rescale O accumulators
        #pragma unroll
        for (int mi = 0; mi < 2; mi++)
            #pragma unroll
            for (int df = 0; df < 8; df++)
                #pragma unroll
                for (int e = 0; e < 4; e++)
                    o_acc[mi][df][e] *= alpha[mi][e];
        // P -> LDS (acc layout -> [q][kv]), then read back as A-fragments
        #pragma unroll
        for (int mi = 0; mi < 2; mi++)
            #pragma unroll
            for (int ni = 0; ni < 2; ni++)
                #pragma unroll
                for (int e = 0; e < 4; e++)
                    P_lds[wid][mi * 16 + g * 4 + e][ni * 16 + r16] = f2bf(p[mi][ni][e]);
        short8 pf[2];
        pf[0] = *reinterpret_cast<const short8*>(&P_lds[wid][r16][g * 8]);
        pf[1] = *reinterpret_cast<const short8*>(&P_lds[wid][16 + r16][g * 8]);
        // ---- O += P V  (V read transposed: contiguous along kv) ----
        #pragma unroll
        for (int df = 0; df < 8; df++) {
            short8 vf = *reinterpret_cast<const short8*>(
                &Vt[(size_t)(df * 16 + r16) * N_TOK + kvb + g * 8]);
            o_acc[0][df] = __builtin_amdgcn_mfma_f32_16x16x32_bf16(pf[0], vf, o_acc[0][df], 0, 0, 0);
            o_acc[1][df] = __builtin_amdgcn_mfma_f32_16x16x32_bf16(pf[1], vf, o_acc[1][df], 0, 0, 0);
        }
    }

    // ---- merge the 4 wave partials ----
    if (r16 == 0) {
        #pragma unroll
        for (int mi = 0; mi < 2; mi++)
            #pragma unroll
            for (int e = 0; e < 4; e++) {
                m_lds[wid][mi * 16 + g * 4 + e] = m_run[mi][e];
                l_lds[wid][mi * 16 + g * 4 + e] = l_run[mi][e];
            }
    }
    __syncthreads();
    float fm[2][4];
    #pragma unroll
    for (int mi = 0; mi < 2; mi++)
        #pragma unroll
        for (int e = 0; e < 4; e++) {
            int row = mi * 16 + g * 4 + e;
            float M = fmaxf(fmaxf(m_lds[0][row], m_lds[1][row]),
                            fmaxf(m_lds[2][row], m_lds[3][row]));
            fm[mi][e] = __expf(m_run[mi][e] - M);
        }
    for (int w = 0; w < 4; w++) {
        if (wid == w) {
            #pragma unroll
            for (int mi = 0; mi < 2; mi++)
                #pragma unroll
                for (int e = 0; e < 4; e++) {
                    int row = mi * 16 + g * 4 + e;
                    #pragma unroll
                    for (int df = 0; df < 8; df++) {
                        float v = o_acc[mi][df][e] * fm[mi][e];
                        int col = df * 16 + r16;
                        if (w == 0) O_merge[row][col] = v;
                        else        O_merge[row][col] += v;
                    }
                }
        }
        __syncthreads();
    }
    // normalize + store (32 rows x 128 cols = 1024 float4s, 4 per thread)
    #pragma unroll
    for (int it = 0; it < 4; it++) {
        int idx = tid + it * 256;
        int row = idx >> 5, c4 = idx & 31;
        float M = fmaxf(fmaxf(m_lds[0][row], m_lds[1][row]),
                        fmaxf(m_lds[2][row], m_lds[3][row]));
        float L = 0.f;
        #pragma unroll
        for (int w = 0; w < 4; w++)
            L += __expf(m_lds[w][row] - M) * l_lds[w][row];
        float4 s = *reinterpret_cast<const float4*>(&O_merge[row][c4 * 4]);
        float inv = 1.0f / L;
        float4 r;
        r.x = s.x * inv; r.y = s.y * inv; r.z = s.z * inv; r.w = s.w * inv;
        *reinterpret_cast<float4*>(&O[(size_t)(qbase + row) * DK + c4 * 4]) = r;
    }
}

extern "C" void kernel_launch(void* const* d_in, const int* in_sizes, int n_in,
                              void* d_out, int out_size, void* d_ws, size_t ws_size,
                              hipStream_t stream) {
    const float* X  = (const float*)d_in[0];
    const float* Wq = (const float*)d_in[1];
    const float* bq = (const float*)d_in[2];
    const float* Wk = (const float*)d_in[3];
    const float* bk = (const float*)d_in[4];
    const float* Wv = (const float*)d_in[5];
    const float* bv = (const float*)d_in[6];
    float* O = (float*)d_out;

    unsigned short* Qb = (unsigned short*)d_ws;
    unsigned short* Kb = Qb + (size_t)N_TOK * DK;
    unsigned short* Vt = Kb + (size_t)N_TOK * DK;

    proj_kernel<<<dim3(64, 3), 256, 0, stream>>>(X, Wq, bq, Wk, bk, Wv, bv, Qb, Kb, Vt);
    attn_kernel<<<dim3(256), 256, 0, stream>>>(Qb, Kb, Vt, O);
}

// Round 2
// 156.738 us; speedup vs baseline: 1.4891x; 1.4891x over previous
//
#include <hip/hip_runtime.h>
#include <hip/hip_bf16.h>

#define N_TOK 8192
#define D_IN  1024
#define DK    128
#define NT    256   // number of 32-row q tiles

typedef __attribute__((ext_vector_type(8))) short short8;
typedef __attribute__((ext_vector_type(4))) float f32x4;

static __device__ __forceinline__ unsigned short f2bf(float f) {
    __hip_bfloat16 h = __float2bfloat16(f);
    return __builtin_bit_cast(unsigned short, h);
}

// ---------------- one-time W transpose: W[k][n] f32 -> Wt[n][k] bf16 ----------------
// grid = (32, 3): 16 k-tiles x 2 n-tiles of 64x64, blockIdx.y = projection.
__global__ __launch_bounds__(256) void wtrans_kernel(
    const float* __restrict__ Wq, const float* __restrict__ Wk,
    const float* __restrict__ Wv, unsigned short* __restrict__ Wt)
{
    __shared__ unsigned short T[64][72];
    const int proj = blockIdx.y;
    const float* W = (proj == 0) ? Wq : (proj == 1) ? Wk : Wv;
    unsigned short* out = Wt + (size_t)proj * DK * D_IN;
    const int k0 = (blockIdx.x & 15) * 64, n0 = (blockIdx.x >> 4) * 64;
    const int tid = threadIdx.x;
    #pragma unroll
    for (int i = 0; i < 4; i++) {
        int e = tid + i * 256;
        int r = e >> 4, c4 = e & 15;
        float4 v = *reinterpret_cast<const float4*>(&W[(size_t)(k0 + r) * DK + n0 + c4 * 4]);
        T[c4 * 4 + 0][r] = f2bf(v.x);
        T[c4 * 4 + 1][r] = f2bf(v.y);
        T[c4 * 4 + 2][r] = f2bf(v.z);
        T[c4 * 4 + 3][r] = f2bf(v.w);
    }
    __syncthreads();
    #pragma unroll
    for (int i = 0; i < 4; i++) {
        int e = tid + i * 256;
        int r = e >> 4, c4 = e & 15;
        *reinterpret_cast<ushort4*>(&out[(size_t)(n0 + r) * D_IN + k0 + c4 * 4]) =
            *reinterpret_cast<const ushort4*>(&T[r][c4 * 4]);
    }
}

// ---------------- QKV projection: out = X @ W + b, bf16 outputs ----------------
// grid = (64, 3). A staged through LDS (f32->bf16); B fragments read directly
// from pre-transposed bf16 Wt (L2-resident). Q,K row-major; V transposed.
__global__ __launch_bounds__(256) void proj_kernel(
    const float* __restrict__ X, const unsigned short* __restrict__ Wt,
    const float* __restrict__ bq, const float* __restrict__ bk,
    const float* __restrict__ bv,
    unsigned short* __restrict__ Qb, unsigned short* __restrict__ Kb,
    unsigned short* __restrict__ Vt)
{
    __shared__ unsigned short As[128][72];  // [m][k], pad 64->72

    const int tid  = threadIdx.x;
    const int wid  = tid >> 6, lane = tid & 63;
    const int g    = lane >> 4, r16 = lane & 15;
    const int wm   = wid >> 1, wn = wid & 1;
    const int mb   = blockIdx.x * 128;
    const int proj = blockIdx.y;

    const unsigned short* Wtp = Wt + (size_t)proj * DK * D_IN;
    const float* bias = (proj == 0) ? bq : (proj == 1) ? bk : bv;

    f32x4 acc[4][4] = {};

    for (int k0 = 0; k0 < D_IN; k0 += 64) {
        #pragma unroll
        for (int i = 0; i < 8; i++) {
            int e = tid + i * 256;          // 2048 float4s
            int r = e >> 4, c4 = e & 15;
            const float4 v = *reinterpret_cast<const float4*>(
                &X[(size_t)(mb + r) * D_IN + k0 + c4 * 4]);
            ushort4 h;
            h.x = f2bf(v.x); h.y = f2bf(v.y); h.z = f2bf(v.z); h.w = f2bf(v.w);
            *reinterpret_cast<ushort4*>(&As[r][c4 * 4]) = h;
        }
        __syncthreads();
        #pragma unroll
        for (int kk = 0; kk < 64; kk += 32) {
            short8 af[4], bfr[4];
            #pragma unroll
            for (int mi = 0; mi < 4; mi++)
                af[mi] = *reinterpret_cast<const short8*>(&As[wm * 64 + mi * 16 + r16][kk + g * 8]);
            #pragma unroll
            for (int ni = 0; ni < 4; ni++)
                bfr[ni] = *reinterpret_cast<const short8*>(
                    &Wtp[(size_t)(wn * 64 + ni * 16 + r16) * D_IN + k0 + kk + g * 8]);
            #pragma unroll
            for (int mi = 0; mi < 4; mi++)
                #pragma unroll
                for (int ni = 0; ni < 4; ni++)
                    acc[mi][ni] = __builtin_amdgcn_mfma_f32_16x16x32_bf16(
                        af[mi], bfr[ni], acc[mi][ni], 0, 0, 0);
        }
        __syncthreads();
    }

    if (proj < 2) {
        unsigned short* out = (proj == 0) ? Qb : Kb;
        #pragma unroll
        for (int ni = 0; ni < 4; ni++) {
            int n = wn * 64 + ni * 16 + r16;
            float b = bias[n];
            #pragma unroll
            for (int mi = 0; mi < 4; mi++) {
                #pragma unroll
                for (int e = 0; e < 4; e++) {
                    int m = mb + wm * 64 + mi * 16 + g * 4 + e;
                    out[(size_t)m * DK + n] = f2bf(acc[mi][ni][e] + b);
                }
            }
        }
    } else {
        #pragma unroll
        for (int ni = 0; ni < 4; ni++) {
            int n = wn * 64 + ni * 16 + r16;
            float b = bias[n];
            #pragma unroll
            for (int mi = 0; mi < 4; mi++) {
                int m0 = mb + wm * 64 + mi * 16 + g * 4;
                ushort4 h;
                h.x = f2bf(acc[mi][ni][0] + b);
                h.y = f2bf(acc[mi][ni][1] + b);
                h.z = f2bf(acc[mi][ni][2] + b);
                h.w = f2bf(acc[mi][ni][3] + b);
                *reinterpret_cast<ushort4*>(&Vt[(size_t)n * N_TOK + m0]) = h;
            }
        }
    }
}

// ---------------- causal flash attention, KV-split partials ----------------
// grid = (256, max_chunks). Block (t, c): q rows [t*32, t*32+32), kv tiles
// [c*chunk_tiles, min(c*chunk_tiles+chunk_tiles, t+1)). Empty -> early exit.
// 4 waves stride the chunk's kv tiles; partial (O, m, l) to workspace.
__global__ __launch_bounds__(256) void attn_partial(
    const unsigned short* __restrict__ Qb, const unsigned short* __restrict__ Kb,
    const unsigned short* __restrict__ Vt,
    float* __restrict__ Opart, float* __restrict__ Mpart, float* __restrict__ Lpart,
    float* __restrict__ O, int chunk_tiles, int max_chunks, int direct)
{
    __shared__ float          O_merge[32][128];        // 16 KB
    __shared__ float          m_lds[4][32], l_lds[4][32];
    __shared__ unsigned short P_lds[4][32][40];        // per-wave P transpose

    const int t = blockIdx.x;
    const int c = blockIdx.y;
    const int j0 = c * chunk_tiles;
    if (j0 > t) return;
    const int jend = min(j0 + chunk_tiles, t + 1);

    const int tid = threadIdx.x;
    const int wid = tid >> 6, lane = tid & 63;
    const int g = lane >> 4, r16 = lane & 15;
    const int qbase = t * 32;
    const float scale = 0.08838834764831845f;  // 1/sqrt(128)

    short8 qf[2][4];
    #pragma unroll
    for (int mi = 0; mi < 2; mi++)
        #pragma unroll
        for (int kd = 0; kd < 4; kd++)
            qf[mi][kd] = *reinterpret_cast<const short8*>(
                &Qb[(size_t)(qbase + mi * 16 + r16) * DK + kd * 32 + g * 8]);

    f32x4 o_acc[2][8] = {};
    float m_run[2][4], l_run[2][4];
    #pragma unroll
    for (int mi = 0; mi < 2; mi++)
        #pragma unroll
        for (int e = 0; e < 4; e++) { m_run[mi][e] = -1e30f; l_run[mi][e] = 0.f; }

    for (int j = j0 + wid; j < jend; j += 4) {
        const int kvb = j * 32;
        // ---- S = Q K^T ----
        f32x4 sacc[2][2] = {};
        #pragma unroll
        for (int kd = 0; kd < 4; kd++) {
            short8 kf[2];
            #pragma unroll
            for (int ni = 0; ni < 2; ni++)
                kf[ni] = *reinterpret_cast<const short8*>(
                    &Kb[(size_t)(kvb + ni * 16 + r16) * DK + kd * 32 + g * 8]);
            #pragma unroll
            for (int mi = 0; mi < 2; mi++)
                #pragma unroll
                for (int ni = 0; ni < 2; ni++)
                    sacc[mi][ni] = __builtin_amdgcn_mfma_f32_16x16x32_bf16(
                        qf[mi][kd], kf[ni], sacc[mi][ni], 0, 0, 0);
        }
        // ---- online softmax (row = mi*16 + g*4 + e, col = ni*16 + r16) ----
        float p[2][2][4], alpha[2][4];
        #pragma unroll
        for (int mi = 0; mi < 2; mi++) {
            #pragma unroll
            for (int e = 0; e < 4; e++) {
                float s0 = sacc[mi][0][e] * scale;
                float s1 = sacc[mi][1][e] * scale;
                if (j == t) {  // diagonal tile: mask col > row
                    int row = mi * 16 + g * 4 + e;
                    if (r16 > row)      s0 = -1e30f;
                    if (16 + r16 > row) s1 = -1e30f;
                }
                float rm = fmaxf(s0, s1);
                rm = fmaxf(rm, __shfl_xor(rm, 1));
                rm = fmaxf(rm, __shfl_xor(rm, 2));
                rm = fmaxf(rm, __shfl_xor(rm, 4));
                rm = fmaxf(rm, __shfl_xor(rm, 8));
                float mnew = fmaxf(m_run[mi][e], rm);
                float a  = __expf(m_run[mi][e] - mnew);
                float p0 = __expf(s0 - mnew);
                float p1 = __expf(s1 - mnew);
                float rs = p0 + p1;
                rs += __shfl_xor(rs, 1);
                rs += __shfl_xor(rs, 2);
                rs += __shfl_xor(rs, 4);
                rs += __shfl_xor(rs, 8);
                l_run[mi][e] = l_run[mi][e] * a + rs;
                m_run[mi][e] = mnew;
                alpha[mi][e] = a;
                p[mi][0][e] = p0; p[mi][1][e] = p1;
            }
        }
        #pragma unroll
        for (int mi = 0; mi < 2; mi++)
            #pragma unroll
            for (int df = 0; df < 8; df++)
                #pragma unroll
                for (int e = 0; e < 4; e++)
                    o_acc[mi][df][e] *= alpha[mi][e];
        #pragma unroll
        for (int mi = 0; mi < 2; mi++)
            #pragma unroll
            for (int ni = 0; ni < 2; ni++)
                #pragma unroll
                for (int e = 0; e < 4; e++)
                    P_lds[wid][mi * 16 + g * 4 + e][ni * 16 + r16] = f2bf(p[mi][ni][e]);
        short8 pf[2];
        pf[0] = *reinterpret_cast<const short8*>(&P_lds[wid][r16][g * 8]);
        pf[1] = *reinterpret_cast<const short8*>(&P_lds[wid][16 + r16][g * 8]);
        // ---- O += P V ----
        #pragma unroll
        for (int df = 0; df < 8; df++) {
            short8 vf = *reinterpret_cast<const short8*>(
                &Vt[(size_t)(df * 16 + r16) * N_TOK + kvb + g * 8]);
            o_acc[0][df] = __builtin_amdgcn_mfma_f32_16x16x32_bf16(pf[0], vf, o_acc[0][df], 0, 0, 0);
            o_acc[1][df] = __builtin_amdgcn_mfma_f32_16x16x32_bf16(pf[1], vf, o_acc[1][df], 0, 0, 0);
        }
    }

    // ---- merge the 4 wave partials ----
    if (r16 == 0) {
        #pragma unroll
        for (int mi = 0; mi < 2; mi++)
            #pragma unroll
            for (int e = 0; e < 4; e++) {
                m_lds[wid][mi * 16 + g * 4 + e] = m_run[mi][e];
                l_lds[wid][mi * 16 + g * 4 + e] = l_run[mi][e];
            }
    }
    __syncthreads();
    float fm[2][4];
    #pragma unroll
    for (int mi = 0; mi < 2; mi++)
        #pragma unroll
        for (int e = 0; e < 4; e++) {
            int row = mi * 16 + g * 4 + e;
            float M = fmaxf(fmaxf(m_lds[0][row], m_lds[1][row]),
                            fmaxf(m_lds[2][row], m_lds[3][row]));
            fm[mi][e] = __expf(m_run[mi][e] - M);
        }
    for (int w = 0; w < 4; w++) {
        if (wid == w) {
            #pragma unroll
            for (int mi = 0; mi < 2; mi++)
                #pragma unroll
                for (int e = 0; e < 4; e++) {
                    int row = mi * 16 + g * 4 + e;
                    #pragma unroll
                    for (int df = 0; df < 8; df++) {
                        float v = o_acc[mi][df][e] * fm[mi][e];
                        int col = df * 16 + r16;
                        if (w == 0) O_merge[row][col] = v;
                        else        O_merge[row][col] += v;
                    }
                }
        }
        __syncthreads();
    }
    // ---- store partial (or direct) ----
    #pragma unroll
    for (int it = 0; it < 4; it++) {
        int idx = tid + it * 256;
        int row = idx >> 5, c4 = idx & 31;
        float M = fmaxf(fmaxf(m_lds[0][row], m_lds[1][row]),
                        fmaxf(m_lds[2][row], m_lds[3][row]));
        float L = 0.f;
        #pragma unroll
        for (int w = 0; w < 4; w++)
            L += __expf(m_lds[w][row] - M) * l_lds[w][row];
        float4 s = *reinterpret_cast<const float4*>(&O_merge[row][c4 * 4]);
        if (direct) {
            float inv = 1.0f / L;
            float4 r;
            r.x = s.x * inv; r.y = s.y * inv; r.z = s.z * inv; r.w = s.w * inv;
            *reinterpret_cast<float4*>(&O[(size_t)(qbase + row) * DK + c4 * 4]) = r;
        } else {
            size_t pb = ((size_t)t * max_chunks + c) * 32 + row;
            *reinterpret_cast<float4*>(&Opart[pb * 128 + c4 * 4]) = s;
            if (c4 == 0) { Mpart[pb] = M; Lpart[pb] = L; }
        }
    }
}

// ---------------- merge partials across chunks ----------------
// grid = 256 blocks, block t merges nc = t/chunk_tiles + 1 partials.
__global__ __launch_bounds__(256) void attn_merge(
    const float* __restrict__ Opart, const float* __restrict__ Mpart,
    const float* __restrict__ Lpart, float* __restrict__ O,
    int chunk_tiles, int max_chunks)
{
    __shared__ float Ms[32], Ls[32], Fs[8][32];
    const int t = blockIdx.x;
    const int nc = t / chunk_tiles + 1;
    const int tid = threadIdx.x;

    if (tid < 32) {
        float M = -1e30f;
        for (int c = 0; c < nc; c++)
            M = fmaxf(M, Mpart[((size_t)t * max_chunks + c) * 32 + tid]);
        float L = 0.f;
        for (int c = 0; c < nc; c++) {
            size_t pb = ((size_t)t * max_chunks + c) * 32 + tid;
            L += __expf(Mpart[pb] - M) * Lpart[pb];
        }
        Ms[tid] = M; Ls[tid] = L;
    }
    __syncthreads();
    {
        int c = tid >> 5, row = tid & 31;
        if (c < nc)
            Fs[c][row] = __expf(Mpart[((size_t)t * max_chunks + c) * 32 + row] - Ms[row]);
    }
    __syncthreads();
    #pragma unroll
    for (int it = 0; it < 4; it++) {
        int idx = tid + it * 256;
        int row = idx >> 5, c4 = idx & 31;
        float4 acc = {0.f, 0.f, 0.f, 0.f};
        for (int c = 0; c < nc; c++) {
            const float4 v = *reinterpret_cast<const float4*>(
                &Opart[(((size_t)t * max_chunks + c) * 32 + row) * 128 + c4 * 4]);
            float f = Fs[c][row];
            acc.x += f * v.x; acc.y += f * v.y; acc.z += f * v.z; acc.w += f * v.w;
        }
        float inv = 1.0f / Ls[row];
        float4 r;
        r.x = acc.x * inv; r.y = acc.y * inv; r.z = acc.z * inv; r.w = acc.w * inv;
        *reinterpret_cast<float4*>(&O[((size_t)t * 32 + row) * DK + c4 * 4]) = r;
    }
}

extern "C" void kernel_launch(void* const* d_in, const int* in_sizes, int n_in,
                              void* d_out, int out_size, void* d_ws, size_t ws_size,
                              hipStream_t stream) {
    const float* X  = (const float*)d_in[0];
    const float* Wq = (const float*)d_in[1];
    const float* bq = (const float*)d_in[2];
    const float* Wk = (const float*)d_in[3];
    const float* bk = (const float*)d_in[4];
    const float* Wv = (const float*)d_in[5];
    const float* bv = (const float*)d_in[6];
    float* O = (float*)d_out;

    unsigned short* Qb = (unsigned short*)d_ws;
    unsigned short* Kb = Qb + (size_t)N_TOK * DK;
    unsigned short* Vt = Kb + (size_t)N_TOK * DK;
    unsigned short* Wt = Vt + (size_t)N_TOK * DK;
    float* Opart = (float*)(Wt + (size_t)3 * DK * D_IN);
    size_t base_bytes = (size_t)((char*)Opart - (char*)d_ws);

    // pick the largest split that fits the workspace
    int chunk_tiles = 0, max_chunks = 1, direct = 0;
    const int opts[4] = {32, 64, 128, 256};
    for (int i = 0; i < 4; i++) {
        int ct = opts[i], mc = NT / ct;
        size_t need = base_bytes + (size_t)NT * mc * 32 * (128 + 2) * sizeof(float);
        if (need <= ws_size) { chunk_tiles = ct; max_chunks = mc; break; }
    }
    if (!chunk_tiles) { chunk_tiles = NT; max_chunks = 1; direct = 1; }
    float* Mpart = Opart + (size_t)NT * max_chunks * 32 * 128;
    float* Lpart = Mpart + (size_t)NT * max_chunks * 32;

    wtrans_kernel<<<dim3(32, 3), 256, 0, stream>>>(Wq, Wk, Wv, Wt);
    proj_kernel<<<dim3(64, 3), 256, 0, stream>>>(X, Wt, bq, bk, bv, Qb, Kb, Vt);
    attn_partial<<<dim3(NT, max_chunks), 256, 0, stream>>>(
        Qb, Kb, Vt, Opart, Mpart, Lpart, O, chunk_tiles, max_chunks, direct);
    if (!direct)
        attn_merge<<<dim3(NT), 256, 0, stream>>>(Opart, Mpart, Lpart, O,
                                                 chunk_tiles, max_chunks);
}